// Round 3
// baseline (407.094 us; speedup 1.0000x reference)
//
#include <hip/hip_runtime.h>
#include <hip/hip_bf16.h>

static constexpr int NHID = 32;

typedef __attribute__((ext_vector_type(8)))  short short8v;  // 8 bf16
typedef __attribute__((ext_vector_type(16))) float f32x16;

union ABfrag { short8v v; short s[8]; };

static __device__ __forceinline__ short f2bf(float f) {
    __hip_bfloat16 h = __float2bfloat16(f);   // RNE
    return __builtin_bit_cast(short, h);
}

// ===========================================================================
// CSR build: cnt=0 ; cnt[dst[e]]++ ; exclusive scan -> rowptr (+cursor) ;
// scatter srcP/eaP in dst-sorted order (intra-segment order is atomic-arrival:
// nondeterministic but only permutes ~2 fp32 addends -> ulp-level).
// ===========================================================================
__global__ __launch_bounds__(256) void sort_zero(int* __restrict__ cnt, int N)
{
    int i = blockIdx.x * 256 + threadIdx.x;
    if (i < N) cnt[i] = 0;
}

__global__ __launch_bounds__(256) void sort_hist(
    const int* __restrict__ dst, int* __restrict__ cnt, int E)
{
    int e = blockIdx.x * 256 + threadIdx.x;
    if (e < E) atomicAdd(&cnt[dst[e]], 1);
}

// single block of 1024 threads; chunk-serial + LDS Hillis-Steele scan
__global__ __launch_bounds__(1024) void sort_scan(
    int* __restrict__ cnt, int* __restrict__ rowptr, int N, int E)
{
    __shared__ int sums[1024];
    const int t = threadIdx.x;
    const int chunk = (N + 1023) >> 10;
    const int i0 = t * chunk;
    const int i1 = (i0 + chunk < N) ? i0 + chunk : N;
    int s = 0;
    for (int i = i0; i < i1; ++i) s += cnt[i];
    sums[t] = s;
    __syncthreads();
    for (int off = 1; off < 1024; off <<= 1) {
        int u = (t >= off) ? sums[t - off] : 0;
        __syncthreads();
        sums[t] += u;
        __syncthreads();
    }
    int run = sums[t] - s;                    // exclusive prefix
    for (int i = i0; i < i1; ++i) {
        int c = cnt[i];
        rowptr[i] = run;
        cnt[i] = run;                         // scatter cursor
        run += c;
    }
    if (t == 1023) rowptr[N] = E;
}

__global__ __launch_bounds__(256) void sort_scatter(
    const int* __restrict__ src, const int* __restrict__ dst,
    const float* __restrict__ ea, int* __restrict__ cursor,
    int* __restrict__ srcP, float* __restrict__ eaP, int E)
{
    int e = blockIdx.x * 256 + threadIdx.x;
    if (e >= E) return;
    int p = atomicAdd(&cursor[dst[e]], 1);
    srcP[p] = src[e];
    float4 a = *reinterpret_cast<const float4*>(ea + 4ll * e);
    *reinterpret_cast<float4*>(eaP + 4ll * p) = a;
}

// ===========================================================================
// B-fragment pre-swizzle for mfma_f32_32x32x16_bf16, all 4 layers in ONE
// launch (blockIdx-range dispatch).  kappa = k*INP + i ; element (t,l,j):
//   kappa = 16*t + 8*(l>>5) + j ; o = l&31
//   t <  2*INP : B = w2[k, i*OUT_C+o]      t >= : B = b2[i*OUT_C+o]
// Out-of-range (i>=IN_C or o>=OUT_C) -> 0.
// ===========================================================================
__global__ __launch_bounds__(256) void build_bswz_all(
    const float* w2a, const float* b2a, short* oa,
    const float* w2b, const float* b2b, short* ob,
    const float* w2c, const float* b2c, short* oc,
    const float* w2d, const float* b2d, short* od)
{
    int b = blockIdx.x;
    const float *w2, *b2; short* out; int INP, IN_C, OUT_C, tid;
    if (b < 34)       { w2=w2a; b2=b2a; out=oa; INP=8;  IN_C=6;  OUT_C=32; tid = b*256 + threadIdx.x; }
    else if (b < 166) { w2=w2b; b2=b2b; out=ob; INP=32; IN_C=32; OUT_C=32; tid = (b-34)*256 + threadIdx.x; }
    else if (b < 298) { w2=w2c; b2=b2c; out=oc; INP=32; IN_C=32; OUT_C=32; tid = (b-166)*256 + threadIdx.x; }
    else              { w2=w2d; b2=b2d; out=od; INP=32; IN_C=32; OUT_C=2;  tid = (b-298)*256 + threadIdx.x; }
    const int S_MAIN = 2 * INP;
    const int S_TOT  = S_MAIN + ((INP + 15) >> 4);
    if (tid >= S_TOT * 512) return;
    int j = tid & 7, l = (tid >> 3) & 63, t = tid >> 9;
    int g = l >> 5, o = l & 31;
    float v = 0.f;
    if (t < S_MAIN) {
        int kap = 16 * t + 8 * g + j;
        int k, i;
        if (INP == 8) { k = kap >> 3; i = kap & 7; }
        else          { k = kap >> 5; i = kap & 31; }
        if (i < IN_C && o < OUT_C)
            v = w2[(size_t)k * (IN_C * OUT_C) + i * OUT_C + o];
    } else {
        int i = 16 * (t - S_MAIN) + 8 * g + j;
        if (i < IN_C && o < OUT_C)
            v = b2[i * OUT_C + o];
    }
    out[tid] = f2bf(v);
}

// ===========================================================================
// Edge kernel: wave = 32 edges, MFMA over K = NHID*INP (+ b2 tail).
// k-outer loop recomputes h_k (5 VALU / 2 MFMA) -> no h[32] register blowup.
// Writes msg rows (dst-sorted order) with plain coalesced stores — NO atomics.
// C layout (m74/m101): col = lane&31 = o, row = (r&3) + 8*(r>>2) + 4*(lane>>5).
// ===========================================================================
template<int INP, int IN_C, int OUT_C, bool RELU_IN, int XSTRIDE, int XOFF>
__global__ __launch_bounds__(256) void nnconv_edge_mfma(
    const float* __restrict__ xfeat,
    const int*   __restrict__ srcP,
    const float* __restrict__ eaP,
    const float* __restrict__ w1,     // (4, 32) row-major
    const float* __restrict__ b1,     // (32)
    const short* __restrict__ bswz,
    float* __restrict__ msg,          // E x OUT_C, dst-sorted
    int E)
{
    const int lane = threadIdx.x & 63;
    const int wid  = (blockIdx.x * 256 + threadIdx.x) >> 6;
    const int e0   = wid * 32;
    if (e0 >= E) return;
    const int g = lane >> 5, o = lane & 31;

    const int er = e0 + (lane & 31);
    const int ec = er < E ? er : (E - 1);
    const int s  = srcP[ec];
    const float4 av = *reinterpret_cast<const float4*>(eaP + 4ll * ec);

    constexpr int NXR = (INP == 32) ? 16 : 8;
    float xr[NXR];
    const float* xp = xfeat + (size_t)s * XSTRIDE + XOFF;
    if constexpr (INP == 32) {
        // lane g holds x[8g..8g+7] and x[16+8g..16+8g+7]
        float4 v0 = *reinterpret_cast<const float4*>(xp + 8 * g);
        float4 v1 = *reinterpret_cast<const float4*>(xp + 8 * g + 4);
        float4 v2 = *reinterpret_cast<const float4*>(xp + 16 + 8 * g);
        float4 v3 = *reinterpret_cast<const float4*>(xp + 16 + 8 * g + 4);
        xr[0]=v0.x; xr[1]=v0.y; xr[2]=v0.z; xr[3]=v0.w;
        xr[4]=v1.x; xr[5]=v1.y; xr[6]=v1.z; xr[7]=v1.w;
        xr[8]=v2.x; xr[9]=v2.y; xr[10]=v2.z; xr[11]=v2.w;
        xr[12]=v3.x; xr[13]=v3.y; xr[14]=v3.z; xr[15]=v3.w;
    } else {
        #pragma unroll
        for (int j = 0; j < 8; ++j) xr[j] = (j < IN_C) ? xp[j] : 0.f;
    }
    if constexpr (RELU_IN) {
        #pragma unroll
        for (int j = 0; j < NXR; ++j) xr[j] = fmaxf(xr[j], 0.f);
    }

    f32x16 C;
    #pragma unroll
    for (int i = 0; i < 16; ++i) C[i] = 0.f;

    const short8v* bp = reinterpret_cast<const short8v*>(bswz);

    if constexpr (INP == 32) {
        #pragma unroll 4
        for (int k = 0; k < NHID; ++k) {
            float hk = fmaf(av.x, w1[k], b1[k]);
            hk = fmaf(av.y, w1[NHID + k], hk);
            hk = fmaf(av.z, w1[2 * NHID + k], hk);
            hk = fmaf(av.w, w1[3 * NHID + k], hk);
            hk = fmaxf(hk, 0.f);
            ABfrag a0, a1;
            #pragma unroll
            for (int j = 0; j < 8; ++j) a0.s[j] = f2bf(hk * xr[j]);
            #pragma unroll
            for (int j = 0; j < 8; ++j) a1.s[j] = f2bf(hk * xr[8 + j]);
            C = __builtin_amdgcn_mfma_f32_32x32x16_bf16(a0.v, bp[(2*k  )*64 + lane], C, 0, 0, 0);
            C = __builtin_amdgcn_mfma_f32_32x32x16_bf16(a1.v, bp[(2*k+1)*64 + lane], C, 0, 0, 0);
        }
        ABfrag a;                                  // b2 tail, h == 1
        #pragma unroll
        for (int j = 0; j < 8; ++j) a.s[j] = f2bf(xr[j]);
        C = __builtin_amdgcn_mfma_f32_32x32x16_bf16(a.v, bp[64*64 + lane], C, 0, 0, 0);
        #pragma unroll
        for (int j = 0; j < 8; ++j) a.s[j] = f2bf(xr[8 + j]);
        C = __builtin_amdgcn_mfma_f32_32x32x16_bf16(a.v, bp[65*64 + lane], C, 0, 0, 0);
    } else {
        #pragma unroll 4
        for (int t = 0; t < 16; ++t) {
            const int k = 2 * t + g;               // lane-dependent -> vector ld
            float hk = fmaf(av.x, w1[k], b1[k]);
            hk = fmaf(av.y, w1[NHID + k], hk);
            hk = fmaf(av.z, w1[2 * NHID + k], hk);
            hk = fmaf(av.w, w1[3 * NHID + k], hk);
            hk = fmaxf(hk, 0.f);
            ABfrag a;
            #pragma unroll
            for (int j = 0; j < 8; ++j) a.s[j] = f2bf(hk * xr[j]);
            C = __builtin_amdgcn_mfma_f32_32x32x16_bf16(a.v, bp[t*64 + lane], C, 0, 0, 0);
        }
        ABfrag a;                                  // b2 tail
        #pragma unroll
        for (int j = 0; j < 8; ++j) a.s[j] = (g == 0) ? f2bf(xr[j]) : (short)0;
        C = __builtin_amdgcn_mfma_f32_32x32x16_bf16(a.v, bp[16*64 + lane], C, 0, 0, 0);
    }

    // plain stores: reg r=4q+m -> edge row 8q+4g+m, col o
    if (e0 + 31 < E) {
        if constexpr (OUT_C == 32) {
            float* mp = msg + (size_t)e0 * 32 + o;
            #pragma unroll
            for (int q = 0; q < 4; ++q)
                #pragma unroll
                for (int m = 0; m < 4; ++m)
                    mp[(size_t)(8*q + 4*g + m) * 32] = C[4*q + m];
        } else {
            if (o < OUT_C) {
                float* mp = msg + (size_t)e0 * OUT_C + o;
                #pragma unroll
                for (int q = 0; q < 4; ++q)
                    #pragma unroll
                    for (int m = 0; m < 4; ++m)
                        mp[(size_t)(8*q + 4*g + m) * OUT_C] = C[4*q + m];
            }
        }
    } else {
        if (o < OUT_C) {
            #pragma unroll
            for (int q = 0; q < 4; ++q)
                #pragma unroll
                for (int m = 0; m < 4; ++m) {
                    int row = e0 + 8*q + 4*g + m;
                    if (row < E) msg[(size_t)row * OUT_C + o] = C[4*q + m];
                }
        }
    }
}

// ===========================================================================
// Segment-sum + fused node term: out[v] = bias + relu?(x[v]) @ root + sum(msg
// rows rowptr[v]..rowptr[v+1]).  Thread = (node, 8-float chunk).
// ===========================================================================
template<int IN_C, int OUT_C, bool RELU_IN, int XSTRIDE, int XOFF>
__global__ __launch_bounds__(256) void nnconv_segsum(
    const float* __restrict__ xfeat,
    const float* __restrict__ msg,
    const int*   __restrict__ rowptr,
    const float* __restrict__ root,
    const float* __restrict__ bias,
    float* __restrict__ outbuf,
    int N)
{
    constexpr int CH = (OUT_C >= 8) ? 8 : OUT_C;
    constexpr int NC = OUT_C / CH;
    int tid = blockIdx.x * 256 + threadIdx.x;
    int v = tid / NC, c = tid % NC;
    if (v >= N) return;
    const int c0 = c * CH;

    float acc[CH];
    #pragma unroll
    for (int j = 0; j < CH; ++j) acc[j] = bias[c0 + j];

    const float* xp = xfeat + (size_t)v * XSTRIDE + XOFF;
    #pragma unroll
    for (int i = 0; i < IN_C; ++i) {
        float xi = xp[i];
        if (RELU_IN) xi = fmaxf(xi, 0.f);
        #pragma unroll
        for (int j = 0; j < CH; ++j)
            acc[j] = fmaf(xi, root[i * OUT_C + c0 + j], acc[j]);
    }

    const int r1 = rowptr[v + 1];
    for (int r = rowptr[v]; r < r1; ++r) {
        const float* mp = msg + (size_t)r * OUT_C + c0;
        if constexpr (CH == 8) {
            float4 m0 = *reinterpret_cast<const float4*>(mp);
            float4 m1 = *reinterpret_cast<const float4*>(mp + 4);
            acc[0] += m0.x; acc[1] += m0.y; acc[2] += m0.z; acc[3] += m0.w;
            acc[4] += m1.x; acc[5] += m1.y; acc[6] += m1.z; acc[7] += m1.w;
        } else {
            #pragma unroll
            for (int j = 0; j < CH; ++j) acc[j] += mp[j];
        }
    }

    float* op = outbuf + (size_t)v * OUT_C + c0;
    #pragma unroll
    for (int j = 0; j < CH; ++j) op[j] = acc[j];
}

// ===========================================================================
extern "C" void kernel_launch(void* const* d_in, const int* in_sizes, int n_in,
                              void* d_out, int out_size, void* d_ws, size_t ws_size,
                              hipStream_t stream)
{
    const float* x  = (const float*)d_in[0];
    const int*   ei = (const int*)d_in[1];
    const float* ea = (const float*)d_in[2];

    const int E = in_sizes[2] / 4;
    const int N = in_sizes[0] / 10;
    const int* src = ei;
    const int* dst = ei + E;

    const float* p[4][6];   // w1, b1, w2, b2, root, bias
    for (int L = 0; L < 4; ++L)
        for (int j = 0; j < 6; ++j)
            p[L][j] = (const float*)d_in[3 + 6 * L + j];

    char* w = (char*)d_ws;
    auto carve = [&](size_t bytes) {
        char* q = w; w += (bytes + 255) & ~(size_t)255; return (void*)q;
    };
    float* A      = (float*)carve((size_t)N * 32 * 4);
    float* Bbuf   = (float*)carve((size_t)N * 32 * 4);
    float* msg    = (float*)carve((size_t)E * 32 * 4);
    float* eaP    = (float*)carve((size_t)E * 4 * 4);
    int*   srcP   = (int*)  carve((size_t)E * 4);
    int*   rowptr = (int*)  carve((size_t)(N + 1) * 4);
    int*   cnt    = (int*)  carve((size_t)N * 4);
    short* bswz0  = (short*)carve(17 * 512 * 2);
    short* bswz1  = (short*)carve(66 * 512 * 2);
    short* bswz2  = (short*)carve(66 * 512 * 2);
    short* bswz3  = (short*)carve(66 * 512 * 2);
    float* out    = (float*)d_out;

    const int nb  = (N + 255) / 256;
    const int ebk = (E + 255) / 256;

    // CSR build
    sort_zero   <<<nb, 256, 0, stream>>>(cnt, N);
    sort_hist   <<<ebk, 256, 0, stream>>>(dst, cnt, E);
    sort_scan   <<<1, 1024, 0, stream>>>(cnt, rowptr, N, E);
    sort_scatter<<<ebk, 256, 0, stream>>>(src, dst, ea, cnt, srcP, eaP, E);

    // all B-fragment swizzles in one launch
    build_bswz_all<<<430, 256, 0, stream>>>(
        p[0][2], p[0][3], bswz0,
        p[1][2], p[1][3], bswz1,
        p[2][2], p[2][3], bswz2,
        p[3][2], p[3][3], bswz3);

    const int nwaves  = (E + 31) / 32;
    const int eblocks = (nwaves + 3) / 4;
    const int segb32  = (N * 4 + 255) / 256;

    // layer 0: x[:,4:10] -> A
    nnconv_edge_mfma<8, 6, 32, false, 10, 4><<<eblocks, 256, 0, stream>>>(
        x, srcP, eaP, p[0][0], p[0][1], bswz0, msg, E);
    nnconv_segsum<6, 32, false, 10, 4><<<segb32, 256, 0, stream>>>(
        x, msg, rowptr, p[0][4], p[0][5], A, N);

    // layer 1: relu(A) -> B
    nnconv_edge_mfma<32, 32, 32, true, 32, 0><<<eblocks, 256, 0, stream>>>(
        A, srcP, eaP, p[1][0], p[1][1], bswz1, msg, E);
    nnconv_segsum<32, 32, true, 32, 0><<<segb32, 256, 0, stream>>>(
        A, msg, rowptr, p[1][4], p[1][5], Bbuf, N);

    // layer 2: relu(B) -> A
    nnconv_edge_mfma<32, 32, 32, true, 32, 0><<<eblocks, 256, 0, stream>>>(
        Bbuf, srcP, eaP, p[2][0], p[2][1], bswz2, msg, E);
    nnconv_segsum<32, 32, true, 32, 0><<<segb32, 256, 0, stream>>>(
        Bbuf, msg, rowptr, p[2][4], p[2][5], A, N);

    // layer 3: relu(A) -> out (N x 2)
    nnconv_edge_mfma<32, 32, 2, true, 32, 0><<<eblocks, 256, 0, stream>>>(
        A, srcP, eaP, p[3][0], p[3][1], bswz3, msg, E);
    nnconv_segsum<32, 2, true, 32, 0><<<nb, 256, 0, stream>>>(
        A, msg, rowptr, p[3][4], p[3][5], out, N);
}

// Round 4
// 189.866 us; speedup vs baseline: 2.1441x; 2.1441x over previous
//
#include <hip/hip_runtime.h>
#include <hip/hip_bf16.h>

static constexpr int NHID = 32;

typedef __attribute__((ext_vector_type(8)))  short short8v;  // 8 bf16
typedef __attribute__((ext_vector_type(16))) float f32x16;

union ABfrag { short8v v; short s[8]; };

static __device__ __forceinline__ short f2bf(float f) {
    __hip_bfloat16 h = __float2bfloat16(f);   // RNE
    return __builtin_bit_cast(short, h);
}

// ===========================================================================
// CSR build: cnt=0 ; cnt[dst[e]]++ ; 3-phase parallel exclusive scan ->
// rowptr (+cursor) ; scatter srcP/eaP dst-sorted (intra-segment order is
// atomic-arrival: permutes ~2 fp32 addends -> ulp-level only).
// ===========================================================================
__global__ __launch_bounds__(256) void sort_zero(int* __restrict__ cnt, int N)
{
    int i = blockIdx.x * 256 + threadIdx.x;
    if (i < N) cnt[i] = 0;
}

__global__ __launch_bounds__(256) void sort_hist(
    const int* __restrict__ dst, int* __restrict__ cnt, int E)
{
    int e = blockIdx.x * 256 + threadIdx.x;
    if (e < E) atomicAdd(&cnt[dst[e]], 1);
}

// phase a: per-block sums of cnt
__global__ __launch_bounds__(256) void scan_part(
    const int* __restrict__ cnt, int* __restrict__ bsum, int N)
{
    __shared__ int lds[256];
    int i = blockIdx.x * 256 + threadIdx.x;
    int v = (i < N) ? cnt[i] : 0;
    lds[threadIdx.x] = v;
    __syncthreads();
    #pragma unroll
    for (int off = 128; off > 0; off >>= 1) {
        if (threadIdx.x < off) lds[threadIdx.x] += lds[threadIdx.x + off];
        __syncthreads();
    }
    if (threadIdx.x == 0) bsum[blockIdx.x] = lds[0];
}

// phase b: single small block, exclusive scan of block sums (nb <= 1024)
__global__ __launch_bounds__(1024) void scan_mid(int* __restrict__ bsum, int nb)
{
    __shared__ int lds[1024];
    int t = threadIdx.x;
    int v = (t < nb) ? bsum[t] : 0;
    lds[t] = v;
    __syncthreads();
    for (int off = 1; off < 1024; off <<= 1) {
        int u = (t >= off) ? lds[t - off] : 0;
        __syncthreads();
        lds[t] += u;
        __syncthreads();
    }
    if (t < nb) bsum[t] = lds[t] - v;          // exclusive
}

// phase c: local exclusive scan + block offset -> rowptr, cursor (aliases cnt)
__global__ __launch_bounds__(256) void scan_final(
    int* __restrict__ cnt, const int* __restrict__ bsum,
    int* __restrict__ rowptr, int N)
{
    __shared__ int lds[256];
    int i = blockIdx.x * 256 + threadIdx.x;
    int v = (i < N) ? cnt[i] : 0;
    lds[threadIdx.x] = v;
    __syncthreads();
    for (int off = 1; off < 256; off <<= 1) {  // inclusive Hillis-Steele
        int u = (threadIdx.x >= off) ? lds[threadIdx.x - off] : 0;
        __syncthreads();
        lds[threadIdx.x] += u;
        __syncthreads();
    }
    int excl = lds[threadIdx.x] - v + bsum[blockIdx.x];
    if (i < N) {
        rowptr[i] = excl;
        cnt[i] = excl;                          // scatter cursor
        if (i == N - 1) rowptr[N] = excl + v;
    }
}

__global__ __launch_bounds__(256) void sort_scatter(
    const int* __restrict__ src, const int* __restrict__ dst,
    const float* __restrict__ ea, int* __restrict__ cursor,
    int* __restrict__ srcP, float* __restrict__ eaP, int E)
{
    int e = blockIdx.x * 256 + threadIdx.x;
    if (e >= E) return;
    int p = atomicAdd(&cursor[dst[e]], 1);
    srcP[p] = src[e];
    float4 a = *reinterpret_cast<const float4*>(ea + 4ll * e);
    *reinterpret_cast<float4*>(eaP + 4ll * p) = a;
}

// ===========================================================================
// B-fragment pre-swizzle for mfma_f32_32x32x16_bf16, all 4 layers in ONE
// launch.  kappa = k*INP + i ; element (t,l,j):
//   kappa = 16*t + 8*(l>>5) + j ; o = l&31
//   t < 2*INP : B = w2[k, i*OUT_C+o]      t >= : B = b2[i*OUT_C+o]
// Out-of-range (i>=IN_C or o>=OUT_C) -> 0.
// ===========================================================================
__global__ __launch_bounds__(256) void build_bswz_all(
    const float* w2a, const float* b2a, short* oa,
    const float* w2b, const float* b2b, short* ob,
    const float* w2c, const float* b2c, short* oc,
    const float* w2d, const float* b2d, short* od)
{
    int b = blockIdx.x;
    const float *w2, *b2; short* out; int INP, IN_C, OUT_C, tid;
    if (b < 34)       { w2=w2a; b2=b2a; out=oa; INP=8;  IN_C=6;  OUT_C=32; tid = b*256 + threadIdx.x; }
    else if (b < 166) { w2=w2b; b2=b2b; out=ob; INP=32; IN_C=32; OUT_C=32; tid = (b-34)*256 + threadIdx.x; }
    else if (b < 298) { w2=w2c; b2=b2c; out=oc; INP=32; IN_C=32; OUT_C=32; tid = (b-166)*256 + threadIdx.x; }
    else              { w2=w2d; b2=b2d; out=od; INP=32; IN_C=32; OUT_C=2;  tid = (b-298)*256 + threadIdx.x; }
    const int S_MAIN = 2 * INP;
    const int S_TOT  = S_MAIN + ((INP + 15) >> 4);
    if (tid >= S_TOT * 512) return;
    int j = tid & 7, l = (tid >> 3) & 63, t = tid >> 9;
    int g = l >> 5, o = l & 31;
    float v = 0.f;
    if (t < S_MAIN) {
        int kap = 16 * t + 8 * g + j;
        int k, i;
        if (INP == 8) { k = kap >> 3; i = kap & 7; }
        else          { k = kap >> 5; i = kap & 31; }
        if (i < IN_C && o < OUT_C)
            v = w2[(size_t)k * (IN_C * OUT_C) + i * OUT_C + o];
    } else {
        int i = 16 * (t - S_MAIN) + 8 * g + j;
        if (i < IN_C && o < OUT_C)
            v = b2[i * OUT_C + o];
    }
    out[tid] = f2bf(v);
}

// ===========================================================================
// Edge kernel: wave = 32 edges, MFMA over K = NHID*INP (+ b2 tail).
// k-outer loop recomputes h_k -> no h[32] register pressure.
// Plain coalesced msg stores (dst-sorted order) — NO atomics.
// C layout (m74/m101): col = lane&31 = o, row = (r&3) + 8*(r>>2) + 4*(lane>>5).
// ===========================================================================
template<int INP, int IN_C, int OUT_C, bool RELU_IN, int XSTRIDE, int XOFF>
__global__ __launch_bounds__(256) void nnconv_edge_mfma(
    const float* __restrict__ xfeat,
    const int*   __restrict__ srcP,
    const float* __restrict__ eaP,
    const float* __restrict__ w1,     // (4, 32) row-major
    const float* __restrict__ b1,     // (32)
    const short* __restrict__ bswz,
    float* __restrict__ msg,          // E x OUT_C, dst-sorted
    int E)
{
    const int lane = threadIdx.x & 63;
    const int wid  = (blockIdx.x * 256 + threadIdx.x) >> 6;
    const int e0   = wid * 32;
    if (e0 >= E) return;
    const int g = lane >> 5, o = lane & 31;

    const int er = e0 + (lane & 31);
    const int ec = er < E ? er : (E - 1);
    const int s  = srcP[ec];
    const float4 av = *reinterpret_cast<const float4*>(eaP + 4ll * ec);

    constexpr int NXR = (INP == 32) ? 16 : 8;
    float xr[NXR];
    const float* xp = xfeat + (size_t)s * XSTRIDE + XOFF;
    if constexpr (INP == 32) {
        float4 v0 = *reinterpret_cast<const float4*>(xp + 8 * g);
        float4 v1 = *reinterpret_cast<const float4*>(xp + 8 * g + 4);
        float4 v2 = *reinterpret_cast<const float4*>(xp + 16 + 8 * g);
        float4 v3 = *reinterpret_cast<const float4*>(xp + 16 + 8 * g + 4);
        xr[0]=v0.x; xr[1]=v0.y; xr[2]=v0.z; xr[3]=v0.w;
        xr[4]=v1.x; xr[5]=v1.y; xr[6]=v1.z; xr[7]=v1.w;
        xr[8]=v2.x; xr[9]=v2.y; xr[10]=v2.z; xr[11]=v2.w;
        xr[12]=v3.x; xr[13]=v3.y; xr[14]=v3.z; xr[15]=v3.w;
    } else {
        #pragma unroll
        for (int j = 0; j < 8; ++j) xr[j] = (j < IN_C) ? xp[j] : 0.f;
    }
    if constexpr (RELU_IN) {
        #pragma unroll
        for (int j = 0; j < NXR; ++j) xr[j] = fmaxf(xr[j], 0.f);
    }

    f32x16 C;
    #pragma unroll
    for (int i = 0; i < 16; ++i) C[i] = 0.f;

    const short8v* bp = reinterpret_cast<const short8v*>(bswz);

    if constexpr (INP == 32) {
        #pragma unroll 4
        for (int k = 0; k < NHID; ++k) {
            float hk = fmaf(av.x, w1[k], b1[k]);
            hk = fmaf(av.y, w1[NHID + k], hk);
            hk = fmaf(av.z, w1[2 * NHID + k], hk);
            hk = fmaf(av.w, w1[3 * NHID + k], hk);
            hk = fmaxf(hk, 0.f);
            ABfrag a0, a1;
            #pragma unroll
            for (int j = 0; j < 8; ++j) a0.s[j] = f2bf(hk * xr[j]);
            #pragma unroll
            for (int j = 0; j < 8; ++j) a1.s[j] = f2bf(hk * xr[8 + j]);
            C = __builtin_amdgcn_mfma_f32_32x32x16_bf16(a0.v, bp[(2*k  )*64 + lane], C, 0, 0, 0);
            C = __builtin_amdgcn_mfma_f32_32x32x16_bf16(a1.v, bp[(2*k+1)*64 + lane], C, 0, 0, 0);
        }
        ABfrag a;                                  // b2 tail, h == 1
        #pragma unroll
        for (int j = 0; j < 8; ++j) a.s[j] = f2bf(xr[j]);
        C = __builtin_amdgcn_mfma_f32_32x32x16_bf16(a.v, bp[64*64 + lane], C, 0, 0, 0);
        #pragma unroll
        for (int j = 0; j < 8; ++j) a.s[j] = f2bf(xr[8 + j]);
        C = __builtin_amdgcn_mfma_f32_32x32x16_bf16(a.v, bp[65*64 + lane], C, 0, 0, 0);
    } else {
        #pragma unroll 4
        for (int t = 0; t < 16; ++t) {
            const int k = 2 * t + g;
            float hk = fmaf(av.x, w1[k], b1[k]);
            hk = fmaf(av.y, w1[NHID + k], hk);
            hk = fmaf(av.z, w1[2 * NHID + k], hk);
            hk = fmaf(av.w, w1[3 * NHID + k], hk);
            hk = fmaxf(hk, 0.f);
            ABfrag a;
            #pragma unroll
            for (int j = 0; j < 8; ++j) a.s[j] = f2bf(hk * xr[j]);
            C = __builtin_amdgcn_mfma_f32_32x32x16_bf16(a.v, bp[t*64 + lane], C, 0, 0, 0);
        }
        ABfrag a;                                  // b2 tail
        #pragma unroll
        for (int j = 0; j < 8; ++j) a.s[j] = (g == 0) ? f2bf(xr[j]) : (short)0;
        C = __builtin_amdgcn_mfma_f32_32x32x16_bf16(a.v, bp[16*64 + lane], C, 0, 0, 0);
    }

    // plain stores: reg r=4q+m -> edge row 8q+4g+m, col o
    if (e0 + 31 < E) {
        if constexpr (OUT_C == 32) {
            float* mp = msg + (size_t)e0 * 32 + o;
            #pragma unroll
            for (int q = 0; q < 4; ++q)
                #pragma unroll
                for (int m = 0; m < 4; ++m)
                    mp[(size_t)(8*q + 4*g + m) * 32] = C[4*q + m];
        } else {
            if (o < OUT_C) {
                float* mp = msg + (size_t)e0 * OUT_C + o;
                #pragma unroll
                for (int q = 0; q < 4; ++q)
                    #pragma unroll
                    for (int m = 0; m < 4; ++m)
                        mp[(size_t)(8*q + 4*g + m) * OUT_C] = C[4*q + m];
            }
        }
    } else {
        if (o < OUT_C) {
            #pragma unroll
            for (int q = 0; q < 4; ++q)
                #pragma unroll
                for (int m = 0; m < 4; ++m) {
                    int row = e0 + 8*q + 4*g + m;
                    if (row < E) msg[(size_t)row * OUT_C + o] = C[4*q + m];
                }
        }
    }
}

// ===========================================================================
// Segment-sum + fused node term: out[v] = bias + relu?(x[v]) @ root + sum of
// msg rows rowptr[v]..rowptr[v+1].  Thread = (node, 8-float chunk).
// ===========================================================================
template<int IN_C, int OUT_C, bool RELU_IN, int XSTRIDE, int XOFF>
__global__ __launch_bounds__(256) void nnconv_segsum(
    const float* __restrict__ xfeat,
    const float* __restrict__ msg,
    const int*   __restrict__ rowptr,
    const float* __restrict__ root,
    const float* __restrict__ bias,
    float* __restrict__ outbuf,
    int N)
{
    constexpr int CH = (OUT_C >= 8) ? 8 : OUT_C;
    constexpr int NC = OUT_C / CH;
    int tid = blockIdx.x * 256 + threadIdx.x;
    int v = tid / NC, c = tid % NC;
    if (v >= N) return;
    const int c0 = c * CH;

    float acc[CH];
    #pragma unroll
    for (int j = 0; j < CH; ++j) acc[j] = bias[c0 + j];

    const float* xp = xfeat + (size_t)v * XSTRIDE + XOFF;
    #pragma unroll
    for (int i = 0; i < IN_C; ++i) {
        float xi = xp[i];
        if (RELU_IN) xi = fmaxf(xi, 0.f);
        #pragma unroll
        for (int j = 0; j < CH; ++j)
            acc[j] = fmaf(xi, root[i * OUT_C + c0 + j], acc[j]);
    }

    const int r1 = rowptr[v + 1];
    for (int r = rowptr[v]; r < r1; ++r) {
        const float* mp = msg + (size_t)r * OUT_C + c0;
        if constexpr (CH == 8) {
            float4 m0 = *reinterpret_cast<const float4*>(mp);
            float4 m1 = *reinterpret_cast<const float4*>(mp + 4);
            acc[0] += m0.x; acc[1] += m0.y; acc[2] += m0.z; acc[3] += m0.w;
            acc[4] += m1.x; acc[5] += m1.y; acc[6] += m1.z; acc[7] += m1.w;
        } else {
            #pragma unroll
            for (int j = 0; j < CH; ++j) acc[j] += mp[j];
        }
    }

    float* op = outbuf + (size_t)v * OUT_C + c0;
    #pragma unroll
    for (int j = 0; j < CH; ++j) op[j] = acc[j];
}

// ===========================================================================
extern "C" void kernel_launch(void* const* d_in, const int* in_sizes, int n_in,
                              void* d_out, int out_size, void* d_ws, size_t ws_size,
                              hipStream_t stream)
{
    const float* x  = (const float*)d_in[0];
    const int*   ei = (const int*)d_in[1];
    const float* ea = (const float*)d_in[2];

    const int E = in_sizes[2] / 4;
    const int N = in_sizes[0] / 10;
    const int* src = ei;
    const int* dst = ei + E;

    const float* p[4][6];   // w1, b1, w2, b2, root, bias
    for (int L = 0; L < 4; ++L)
        for (int j = 0; j < 6; ++j)
            p[L][j] = (const float*)d_in[3 + 6 * L + j];

    char* w = (char*)d_ws;
    auto carve = [&](size_t bytes) {
        char* q = w; w += (bytes + 255) & ~(size_t)255; return (void*)q;
    };
    float* A      = (float*)carve((size_t)N * 32 * 4);
    float* Bbuf   = (float*)carve((size_t)N * 32 * 4);
    float* msg    = (float*)carve((size_t)E * 32 * 4);
    float* eaP    = (float*)carve((size_t)E * 4 * 4);
    int*   srcP   = (int*)  carve((size_t)E * 4);
    int*   rowptr = (int*)  carve((size_t)(N + 1) * 4);
    int*   cnt    = (int*)  carve((size_t)N * 4);
    int*   bsum   = (int*)  carve(1024 * 4);
    short* bswz0  = (short*)carve(17 * 512 * 2);
    short* bswz1  = (short*)carve(66 * 512 * 2);
    short* bswz2  = (short*)carve(66 * 512 * 2);
    short* bswz3  = (short*)carve(66 * 512 * 2);
    float* out    = (float*)d_out;

    const int nb  = (N + 255) / 256;      // 391 for N=100000 (<=1024 req'd)
    const int ebk = (E + 255) / 256;

    // CSR build (parallel scan)
    sort_zero   <<<nb, 256, 0, stream>>>(cnt, N);
    sort_hist   <<<ebk, 256, 0, stream>>>(dst, cnt, E);
    scan_part   <<<nb, 256, 0, stream>>>(cnt, bsum, N);
    scan_mid    <<<1, 1024, 0, stream>>>(bsum, nb);
    scan_final  <<<nb, 256, 0, stream>>>(cnt, bsum, rowptr, N);
    sort_scatter<<<ebk, 256, 0, stream>>>(src, dst, ea, cnt, srcP, eaP, E);

    // all B-fragment swizzles in one launch
    build_bswz_all<<<430, 256, 0, stream>>>(
        p[0][2], p[0][3], bswz0,
        p[1][2], p[1][3], bswz1,
        p[2][2], p[2][3], bswz2,
        p[3][2], p[3][3], bswz3);

    const int nwaves  = (E + 31) / 32;
    const int eblocks = (nwaves + 3) / 4;
    const int segb32  = (N * 4 + 255) / 256;

    // layer 0: x[:,4:10] -> A
    nnconv_edge_mfma<8, 6, 32, false, 10, 4><<<eblocks, 256, 0, stream>>>(
        x, srcP, eaP, p[0][0], p[0][1], bswz0, msg, E);
    nnconv_segsum<6, 32, false, 10, 4><<<segb32, 256, 0, stream>>>(
        x, msg, rowptr, p[0][4], p[0][5], A, N);

    // layer 1: relu(A) -> B
    nnconv_edge_mfma<32, 32, 32, true, 32, 0><<<eblocks, 256, 0, stream>>>(
        A, srcP, eaP, p[1][0], p[1][1], bswz1, msg, E);
    nnconv_segsum<32, 32, true, 32, 0><<<segb32, 256, 0, stream>>>(
        A, msg, rowptr, p[1][4], p[1][5], Bbuf, N);

    // layer 2: relu(B) -> A
    nnconv_edge_mfma<32, 32, 32, true, 32, 0><<<eblocks, 256, 0, stream>>>(
        Bbuf, srcP, eaP, p[2][0], p[2][1], bswz2, msg, E);
    nnconv_segsum<32, 32, true, 32, 0><<<segb32, 256, 0, stream>>>(
        Bbuf, msg, rowptr, p[2][4], p[2][5], A, N);

    // layer 3: relu(A) -> out (N x 2)
    nnconv_edge_mfma<32, 32, 2, true, 32, 0><<<eblocks, 256, 0, stream>>>(
        A, srcP, eaP, p[3][0], p[3][1], bswz3, msg, E);
    nnconv_segsum<32, 2, true, 32, 0><<<nb, 256, 0, stream>>>(
        A, msg, rowptr, p[3][4], p[3][5], out, N);
}